// Round 9
// baseline (202.605 us; speedup 1.0000x reference)
//
#include <hip/hip_runtime.h>
#include <hip/hip_bf16.h>

#define B_    128
#define N_    4096
#define DIM_  16
#define HID_  128
#define NT_   8             // grid.x tiles -> 1024 blocks, 3 resident/CU
#define ROWS_ (N_ / NT_)    // 512 adj rows per block

typedef __bf16 bf16x2 __attribute__((ext_vector_type(2)));
typedef __bf16 bf16x8 __attribute__((ext_vector_type(8)));
typedef float floatx16 __attribute__((ext_vector_type(16)));
typedef unsigned int u32;
typedef unsigned int u32x4 __attribute__((ext_vector_type(4)));

__device__ inline bf16x8 load_cvt8(const float* __restrict__ p) {
  const float4 u = *(const float4*)p;
  const float4 v = *(const float4*)(p + 4);
  bf16x8 r;
  r[0] = (__bf16)u.x; r[1] = (__bf16)u.y; r[2] = (__bf16)u.z; r[3] = (__bf16)u.w;
  r[4] = (__bf16)v.x; r[5] = (__bf16)v.y; r[6] = (__bf16)v.z; r[7] = (__bf16)v.w;
  return r;
}

__device__ inline u32 pk2(float a, float b) {
  bf16x2 p; p[0] = (__bf16)a; p[1] = (__bf16)b;
  return __builtin_bit_cast(u32, p);
}

// R9 = R6's exact wave-tile (32 rows x 128 cols, no spill at 152 live regs)
// with NT_=8 (1024 blocks) + __launch_bounds__(256,3): 3 blocks/CU resident
// instead of the grid-capped 2. Same total per-CU work; 1.5x latency hiding.
// Barrier-free loop, ballot compaction, spare-K bias MFMA, XOR-swizzled sW2.
__global__ __launch_bounds__(256, 3) void edge_kernel(
    const float* __restrict__ x, const float* __restrict__ adj,
    const float* __restrict__ W1, const float* __restrict__ b1,
    const float* __restrict__ W2, const float* __restrict__ b2,
    const int* __restrict__ ip, float* __restrict__ part)
{
  // W2^T swizzled: col c = 128 contiguous bf16 (16 granules of 8);
  // granule g (k=8g..8g+7) stored at slot g ^ (c & 15).
  __shared__ __align__(16) __bf16 sW2[HID_ * HID_];
  __shared__ __align__(16) float sW1s[DIM_][HID_];   // W1 starter rows, coalesced staged
  __shared__ int   sIdx[ROWS_ + 192];
  __shared__ float sAcc[HID_];
  __shared__ float sB1[HID_];
  __shared__ float sEnder[DIM_];
  __shared__ int   sCnt;

  const int t  = threadIdx.x;
  const int b  = blockIdx.y;
  const int n0 = blockIdx.x * ROWS_;
  const int ii = __ldg(ip);

  const int wave = t >> 6, lane = t & 63;
  const int half = lane >> 5, l31 = lane & 31;

  if (t == 0) sCnt = 0;
  if (t < HID_) sAcc[t] = 0.f;
  if (t < DIM_) sEnder[t] = x[((size_t)b * N_ + ii) * DIM_ + t];
  __syncthreads();

  // ---- ballot-based compaction: 1 LDS atomic per wave-iter ----
  #pragma unroll
  for (int r = t; r < ROWS_; r += 256) {
    const bool act = adj[n0 + r] != 0.f;
    const unsigned long long m = __ballot(act);
    int base = 0;
    if (lane == 0) base = atomicAdd(&sCnt, __popcll(m));
    base = __shfl(base, 0);
    if (act) {
      const int pre = __builtin_amdgcn_mbcnt_hi((u32)(m >> 32),
                      __builtin_amdgcn_mbcnt_lo((u32)m, 0));
      sIdx[base + pre] = n0 + r;
    }
  }

  // ---- W1 starter rows -> LDS, fully coalesced ----
  #pragma unroll
  for (int e = t; e < DIM_ * HID_; e += 256) sW1s[e >> 7][e & 127] = W1[e];

  // ---- stage W2^T into LDS, bf16, XOR-swizzled granules ----
  #pragma unroll
  for (int e = 0; e < 8; ++e) {
    const int G = t * 8 + e;            // granule id: c = G>>4, gg = G&15
    const int c = G >> 4, gg = G & 15;
    bf16x8 v;
    #pragma unroll
    for (int j = 0; j < 8; ++j) v[j] = (__bf16)W2[((gg << 3) + j) * HID_ + c];
    *(bf16x8*)&sW2[(c << 7) + ((gg ^ (c & 15)) << 3)] = v;
  }

  // ---- cooperative ender-fold: sB1[f] = b1[f] + ender . W1[16:32, f] ----
  if (t < HID_) {
    float s = b1[t];
    #pragma unroll
    for (int k = 0; k < DIM_; ++k) s += sEnder[k] * W1[(DIM_ + k) * HID_ + t];
    sB1[t] = s;
  }

  const float bv0 = b2[l31], bv1 = b2[32 + l31], bv2 = b2[64 + l31], bv3 = b2[96 + l31];

  __syncthreads();                       // sIdx/sCnt/sW2/sW1s/sB1 ready
  const int cnt = sCnt;
  const int nch = (cnt + 31) >> 5;
  const int end = nch * 32;
  for (int p = cnt + t; p < end + 160; p += 256) sIdx[p] = n0;  // pad + prefetch slack

  // W1^T A-frags from LDS (m=feat=l31+32ft, k=half*8+j); conflict-free (bank=l31)
  bf16x8 w1f[4];
  #pragma unroll
  for (int ft = 0; ft < 4; ++ft) {
    bf16x8 v;
    #pragma unroll
    for (int j = 0; j < 8; ++j) v[j] = (__bf16)sW1s[half * 8 + j][ft * 32 + l31];
    w1f[ft] = v;
  }

  // bias delivered via spare-K MFMA (k=0: bf16 hi, k=1: bf16 residual)
  bf16x8 a2f[4], onef;
  #pragma unroll
  for (int j = 0; j < 8; ++j) onef[j] = (__bf16)0.f;
  if (half == 0) { onef[0] = (__bf16)1.f; onef[1] = (__bf16)1.f; }
  #pragma unroll
  for (int ft = 0; ft < 4; ++ft) {
    bf16x8 v;
    #pragma unroll
    for (int j = 0; j < 8; ++j) v[j] = (__bf16)0.f;
    if (half == 0) {
      const float s = sB1[ft * 32 + l31];
      const __bf16 hi = (__bf16)s;
      v[0] = hi;
      v[1] = (__bf16)(s - (float)hi);
    }
    a2f[ft] = v;
  }
  __syncthreads();                       // pad visible

  float sum0 = 0.f, sum1 = 0.f, sum2 = 0.f, sum3 = 0.f;
  floatx16 zf;
  #pragma unroll
  for (int r = 0; r < 16; ++r) zf[r] = 0.f;

  // prefetch first gather (pad guarantees sIdx valid)
  int cb = wave * 32;
  bf16x8 xf;
  {
    const int row = sIdx[cb + l31];
    xf = load_cvt8(&x[((size_t)b * N_ + row) * DIM_ + half * 8]);
  }

  for (; cb < end; cb += 128) {
    const int nrow = sIdx[cb + 128 + l31];           // next iter (pad-safe)

    // ---- stage A: h1^T tiles (feat on regs, row on l31), bias via MFMA ----
    bf16x8 af[8];                        // stage-B A-frags, k = s*16 + half*8 + j
    #pragma unroll
    for (int ft = 0; ft < 4; ++ft) {
      floatx16 hc = __builtin_amdgcn_mfma_f32_32x32x16_bf16(w1f[ft], xf, zf, 0, 0, 0);
      hc = __builtin_amdgcn_mfma_f32_32x32x16_bf16(a2f[ft], onef, hc, 0, 0, 0);
      #pragma unroll
      for (int sg = 0; sg < 2; ++sg) {
        float e0 = fmaxf(hc[8*sg+0], 0.f), e1 = fmaxf(hc[8*sg+1], 0.f);
        float e2 = fmaxf(hc[8*sg+2], 0.f), e3 = fmaxf(hc[8*sg+3], 0.f);
        float e4 = fmaxf(hc[8*sg+4], 0.f), e5 = fmaxf(hc[8*sg+5], 0.f);
        float e6 = fmaxf(hc[8*sg+6], 0.f), e7 = fmaxf(hc[8*sg+7], 0.f);
        const u32 lo0 = pk2(e0, e1), lo1 = pk2(e2, e3);
        const u32 hi0 = pk2(e4, e5), hi1 = pk2(e6, e7);
        const u32 sA = half ? lo0 : hi0;
        const u32 sB = half ? lo1 : hi1;
        const u32 rA = (u32)__shfl_xor((int)sA, 32);
        const u32 rB = (u32)__shfl_xor((int)sB, 32);
        u32x4 d;
        d[0] = half ? rA : lo0;
        d[1] = half ? rB : lo1;
        d[2] = half ? hi0 : rA;
        d[3] = half ? hi1 : rB;
        af[ft * 2 + sg] = __builtin_bit_cast(bf16x8, d);
      }
    }

    // prefetch next x gather; its waitcnt lands after stage B
    const bf16x8 nxf = load_cvt8(&x[((size_t)b * N_ + nrow) * DIM_ + half * 8]);

    // ---- stage B: 32 rows x 128 cols, K=128; B-frags from swizzled LDS ----
    floatx16 c0 = zf, c1 = zf, c2 = zf, c3 = zf;
    #pragma unroll
    for (int s = 0; s < 8; ++s) {
      const int gp = ((s << 1) + half) ^ (l31 & 15);
      const __bf16* wp = &sW2[(l31 << 7) + (gp << 3)];
      const bf16x8 wb0 = *(const bf16x8*)(wp);
      const bf16x8 wb1 = *(const bf16x8*)(wp + (32 << 7));
      const bf16x8 wb2 = *(const bf16x8*)(wp + (64 << 7));
      const bf16x8 wb3 = *(const bf16x8*)(wp + (96 << 7));
      c0 = __builtin_amdgcn_mfma_f32_32x32x16_bf16(af[s], wb0, c0, 0, 0, 0);
      c1 = __builtin_amdgcn_mfma_f32_32x32x16_bf16(af[s], wb1, c1, 0, 0, 0);
      c2 = __builtin_amdgcn_mfma_f32_32x32x16_bf16(af[s], wb2, c2, 0, 0, 0);
      c3 = __builtin_amdgcn_mfma_f32_32x32x16_bf16(af[s], wb3, c3, 0, 0, 0);
    }

    // ---- epilogue: bias + relu + row-sum (row m=(r&3)+8*(r>>2)+4*half) ----
    if (cb + 32 <= cnt) {
      #pragma unroll
      for (int r = 0; r < 16; ++r) {
        sum0 += fmaxf(c0[r] + bv0, 0.f);
        sum1 += fmaxf(c1[r] + bv1, 0.f);
        sum2 += fmaxf(c2[r] + bv2, 0.f);
        sum3 += fmaxf(c3[r] + bv3, 0.f);
      }
    } else {
      #pragma unroll
      for (int r = 0; r < 16; ++r) {
        const int q = cb + (r & 3) + ((r >> 2) << 3) + (half << 2);
        if (q < cnt) {
          sum0 += fmaxf(c0[r] + bv0, 0.f);
          sum1 += fmaxf(c1[r] + bv1, 0.f);
          sum2 += fmaxf(c2[r] + bv2, 0.f);
          sum3 += fmaxf(c3[r] + bv3, 0.f);
        }
      }
    }
    xf = nxf;
  }

  // fold halves, one LDS atomic per (col, wave)
  sum0 += __shfl_xor(sum0, 32);
  sum1 += __shfl_xor(sum1, 32);
  sum2 += __shfl_xor(sum2, 32);
  sum3 += __shfl_xor(sum3, 32);
  if (half == 0) {
    atomicAdd(&sAcc[l31],      sum0);
    atomicAdd(&sAcc[32 + l31], sum1);
    atomicAdd(&sAcc[64 + l31], sum2);
    atomicAdd(&sAcc[96 + l31], sum3);
  }
  __syncthreads();
  if (t < HID_) part[((size_t)b * NT_ + blockIdx.x) * HID_ + t] = sAcc[t];
}

// acc = sum partials; h3 = relu(acc@W3+b3); h4 = relu(h3@W4+b4);
// out = [x[:,i,:] | h4] @ W5 + b5   (all fp32, exact)
__global__ void tail_kernel(
    const float* __restrict__ x, const float* __restrict__ part,
    const float* __restrict__ W3, const float* __restrict__ b3,
    const float* __restrict__ W4, const float* __restrict__ b4,
    const float* __restrict__ W5, const float* __restrict__ b5,
    const int* __restrict__ ip, float* __restrict__ out)
{
  const int b = blockIdx.x, t = threadIdx.x;   // 128 threads
  __shared__ float s0[HID_], s1[HID_], s2[HID_], se[DIM_];
  const int ii = __ldg(ip);
  if (t < DIM_) se[t] = x[((size_t)b * N_ + ii) * DIM_ + t];
  float a = 0.f;
  #pragma unroll
  for (int p = 0; p < NT_; ++p) a += part[((size_t)b * NT_ + p) * HID_ + t];
  s0[t] = a;
  __syncthreads();
  float v = b3[t];
  #pragma unroll 16
  for (int k = 0; k < HID_; ++k) v += s0[k] * W3[k * HID_ + t];
  s1[t] = fmaxf(v, 0.f);
  __syncthreads();
  float w = b4[t];
  #pragma unroll 16
  for (int k = 0; k < HID_; ++k) w += s1[k] * W4[k * HID_ + t];
  s2[t] = fmaxf(w, 0.f);
  __syncthreads();
  if (t < DIM_) {
    float o = b5[t];
    #pragma unroll
    for (int k = 0; k < DIM_; ++k) o += se[k] * W5[k * DIM_ + t];
    #pragma unroll 16
    for (int k = 0; k < HID_; ++k) o += s2[k] * W5[(DIM_ + k) * DIM_ + t];
    out[b * DIM_ + t] = o;
  }
}

extern "C" void kernel_launch(void* const* d_in, const int* in_sizes, int n_in,
                              void* d_out, int out_size, void* d_ws, size_t ws_size,
                              hipStream_t stream) {
  const float* x   = (const float*)d_in[0];
  const float* adj = (const float*)d_in[1];
  const float* W1  = (const float*)d_in[2];   // W_n2e [32,128]
  const float* b1  = (const float*)d_in[3];
  const float* W2  = (const float*)d_in[4];   // W_e2e [128,128]
  const float* b2  = (const float*)d_in[5];
  const float* W3  = (const float*)d_in[6];   // W_e2n
  const float* b3  = (const float*)d_in[7];
  const float* W4  = (const float*)d_in[8];   // W_n2n
  const float* b4  = (const float*)d_in[9];
  const float* W5  = (const float*)d_in[10];  // W_out [144,16]
  const float* b5  = (const float*)d_in[11];
  const int*   ip  = (const int*)d_in[12];
  float* out  = (float*)d_out;
  float* part = (float*)d_ws;                 // [B, NT_, HID] fp32 partials

  edge_kernel<<<dim3(NT_, B_), 256, 0, stream>>>(x, adj, W1, b1, W2, b2, ip, part);
  tail_kernel<<<B_, HID_, 0, stream>>>(x, part, W3, b3, W4, b4, W5, b5, ip, out);
}

// Round 10
// 123.755 us; speedup vs baseline: 1.6371x; 1.6371x over previous
//
#include <hip/hip_runtime.h>
#include <hip/hip_bf16.h>

#define B_    128
#define N_    4096
#define DIM_  16
#define HID_  128
#define NT_   4             // grid.x tiles -> 512 blocks, 2 resident/CU
#define ROWS_ (N_ / NT_)    // 1024 adj rows per block

typedef __bf16 bf16x2 __attribute__((ext_vector_type(2)));
typedef __bf16 bf16x8 __attribute__((ext_vector_type(8)));
typedef float floatx16 __attribute__((ext_vector_type(16)));
typedef unsigned int u32;
typedef unsigned int u32x4 __attribute__((ext_vector_type(4)));

__device__ inline bf16x8 load_cvt8(const float* __restrict__ p) {
  const float4 u = *(const float4*)p;
  const float4 v = *(const float4*)(p + 4);
  bf16x8 r;
  r[0] = (__bf16)u.x; r[1] = (__bf16)u.y; r[2] = (__bf16)u.z; r[3] = (__bf16)u.w;
  r[4] = (__bf16)v.x; r[5] = (__bf16)v.y; r[6] = (__bf16)v.z; r[7] = (__bf16)v.w;
  return r;
}

__device__ inline u32 pk2(float a, float b) {
  bf16x2 p; p[0] = (__bf16)a; p[1] = (__bf16)b;
  return __builtin_bit_cast(u32, p);
}

// R10: (256,2) proven envelope; wave tile 32 rows x 64 cols. Each wave pulls
// its col-half's W2 B-frags from swizzled LDS ONCE (16 x ds_read_b128 = 64
// VGPRs) -> main loop has ZERO LDS reads (only 16 repack swizzles + sIdx).
// Stage A (all 128 h1 feats, K=128) recomputed per col-half (MFMA is idle
// anyway). Ballot compaction, spare-K bias MFMA, one-ahead x prefetch.
__global__ __launch_bounds__(256, 2) void edge_kernel(
    const float* __restrict__ x, const float* __restrict__ adj,
    const float* __restrict__ W1, const float* __restrict__ b1,
    const float* __restrict__ W2, const float* __restrict__ b2,
    const int* __restrict__ ip, float* __restrict__ part)
{
  // W2^T swizzled: col c = 128 contiguous bf16 (16 granules of 8);
  // granule g (k=8g..8g+7) stored at slot g ^ (c & 15).
  __shared__ __align__(16) __bf16 sW2[HID_ * HID_];
  __shared__ __align__(16) float sW1s[DIM_][HID_];   // W1 starter rows, coalesced staged
  __shared__ int   sIdx[ROWS_ + 192];
  __shared__ float sAcc[HID_];
  __shared__ float sB1[HID_];
  __shared__ float sEnder[DIM_];
  __shared__ int   sCnt;

  const int t  = threadIdx.x;
  const int b  = blockIdx.y;
  const int n0 = blockIdx.x * ROWS_;
  const int ii = __ldg(ip);

  const int wave = t >> 6, lane = t & 63;
  const int half = lane >> 5, l31 = lane & 31;
  const int rg = wave >> 1;           // row-group: chunks rg*32, step 64
  const int ch = wave & 1;            // col-half: cols ch*64 .. ch*64+63

  if (t == 0) sCnt = 0;
  if (t < HID_) sAcc[t] = 0.f;
  if (t < DIM_) sEnder[t] = x[((size_t)b * N_ + ii) * DIM_ + t];
  __syncthreads();

  // ---- ballot-based compaction: 1 LDS atomic per wave-iter ----
  #pragma unroll
  for (int r = t; r < ROWS_; r += 256) {
    const bool act = adj[n0 + r] != 0.f;
    const unsigned long long m = __ballot(act);
    int base = 0;
    if (lane == 0) base = atomicAdd(&sCnt, __popcll(m));
    base = __shfl(base, 0);
    if (act) {
      const int pre = __builtin_amdgcn_mbcnt_hi((u32)(m >> 32),
                      __builtin_amdgcn_mbcnt_lo((u32)m, 0));
      sIdx[base + pre] = n0 + r;
    }
  }

  // ---- W1 starter rows -> LDS, fully coalesced ----
  #pragma unroll
  for (int e = t; e < DIM_ * HID_; e += 256) sW1s[e >> 7][e & 127] = W1[e];

  // ---- stage W2^T into LDS, bf16, XOR-swizzled granules ----
  #pragma unroll
  for (int e = 0; e < 8; ++e) {
    const int G = t * 8 + e;            // granule id: c = G>>4, gg = G&15
    const int c = G >> 4, gg = G & 15;
    bf16x8 v;
    #pragma unroll
    for (int j = 0; j < 8; ++j) v[j] = (__bf16)W2[((gg << 3) + j) * HID_ + c];
    *(bf16x8*)&sW2[(c << 7) + ((gg ^ (c & 15)) << 3)] = v;
  }

  // ---- cooperative ender-fold: sB1[f] = b1[f] + ender . W1[16:32, f] ----
  if (t < HID_) {
    float s = b1[t];
    #pragma unroll
    for (int k = 0; k < DIM_; ++k) s += sEnder[k] * W1[(DIM_ + k) * HID_ + t];
    sB1[t] = s;
  }

  const float bv0 = b2[ch * 64 + l31], bv1 = b2[ch * 64 + 32 + l31];

  __syncthreads();                       // sIdx/sCnt/sW2/sW1s/sB1 ready
  const int cnt = sCnt;
  const int nch64 = (cnt + 63) >> 6;
  const int end = nch64 * 64;
  for (int p = cnt + t; p < end + 128; p += 256) sIdx[p] = n0;  // pad + prefetch slack

  // W1^T A-frags from LDS (m=feat=l31+32ft, k=half*8+j)
  bf16x8 w1f[4];
  #pragma unroll
  for (int ft = 0; ft < 4; ++ft) {
    bf16x8 v;
    #pragma unroll
    for (int j = 0; j < 8; ++j) v[j] = (__bf16)sW1s[half * 8 + j][ft * 32 + l31];
    w1f[ft] = v;
  }

  // ---- W2 B-frags for this wave's col-half: read ONCE from swizzled LDS ----
  // frag k-range: k = s*16 + half*8 + j  -> granule 2s+half, slot ^ (c&15)
  bf16x8 w2r[16];                        // [s] = col-tile0, [8+s] = col-tile1
  {
    const int c0 = ch * 64 + l31;
    const __bf16* base0 = &sW2[(c0 << 7)];
    const __bf16* base1 = &sW2[((c0 + 32) << 7)];
    #pragma unroll
    for (int s = 0; s < 8; ++s) {
      const int gp = ((s << 1) + half) ^ (c0 & 15);
      w2r[s]     = *(const bf16x8*)(base0 + (gp << 3));
      w2r[8 + s] = *(const bf16x8*)(base1 + (gp << 3));
    }
  }

  // bias delivered via spare-K MFMA (k=0: bf16 hi, k=1: bf16 residual)
  bf16x8 a2f[4], onef;
  #pragma unroll
  for (int j = 0; j < 8; ++j) onef[j] = (__bf16)0.f;
  if (half == 0) { onef[0] = (__bf16)1.f; onef[1] = (__bf16)1.f; }
  #pragma unroll
  for (int ft = 0; ft < 4; ++ft) {
    bf16x8 v;
    #pragma unroll
    for (int j = 0; j < 8; ++j) v[j] = (__bf16)0.f;
    if (half == 0) {
      const float s = sB1[ft * 32 + l31];
      const __bf16 hi = (__bf16)s;
      v[0] = hi;
      v[1] = (__bf16)(s - (float)hi);
    }
    a2f[ft] = v;
  }
  __syncthreads();                       // pad visible

  float sum0 = 0.f, sum1 = 0.f;
  floatx16 zf;
  #pragma unroll
  for (int r = 0; r < 16; ++r) zf[r] = 0.f;

  // prefetch first gather (pad guarantees sIdx valid)
  int cb = rg * 32;
  bf16x8 xf;
  {
    const int row = sIdx[cb + l31];
    xf = load_cvt8(&x[((size_t)b * N_ + row) * DIM_ + half * 8]);
  }

  for (; cb < end; cb += 64) {
    const int nrow = sIdx[cb + 64 + l31];            // next iter (pad-safe)

    // ---- stage A: h1^T tiles (feat on regs, row on l31), bias via MFMA ----
    bf16x8 af[8];                        // stage-B A-frags, k = s*16 + half*8 + j
    #pragma unroll
    for (int ft = 0; ft < 4; ++ft) {
      floatx16 hc = __builtin_amdgcn_mfma_f32_32x32x16_bf16(w1f[ft], xf, zf, 0, 0, 0);
      hc = __builtin_amdgcn_mfma_f32_32x32x16_bf16(a2f[ft], onef, hc, 0, 0, 0);
      #pragma unroll
      for (int sg = 0; sg < 2; ++sg) {
        float e0 = fmaxf(hc[8*sg+0], 0.f), e1 = fmaxf(hc[8*sg+1], 0.f);
        float e2 = fmaxf(hc[8*sg+2], 0.f), e3 = fmaxf(hc[8*sg+3], 0.f);
        float e4 = fmaxf(hc[8*sg+4], 0.f), e5 = fmaxf(hc[8*sg+5], 0.f);
        float e6 = fmaxf(hc[8*sg+6], 0.f), e7 = fmaxf(hc[8*sg+7], 0.f);
        const u32 lo0 = pk2(e0, e1), lo1 = pk2(e2, e3);
        const u32 hi0 = pk2(e4, e5), hi1 = pk2(e6, e7);
        const u32 sA = half ? lo0 : hi0;
        const u32 sB = half ? lo1 : hi1;
        const u32 rA = (u32)__shfl_xor((int)sA, 32);
        const u32 rB = (u32)__shfl_xor((int)sB, 32);
        u32x4 d;
        d[0] = half ? rA : lo0;
        d[1] = half ? rB : lo1;
        d[2] = half ? hi0 : rA;
        d[3] = half ? hi1 : rB;
        af[ft * 2 + sg] = __builtin_bit_cast(bf16x8, d);
      }
    }

    // prefetch next x gather; its waitcnt lands after stage B
    const bf16x8 nxf = load_cvt8(&x[((size_t)b * N_ + nrow) * DIM_ + half * 8]);

    // ---- stage B: 32 rows x 64 cols, K=128; B-frags from REGISTERS ----
    floatx16 c0 = zf, c1 = zf;
    #pragma unroll
    for (int s = 0; s < 8; ++s) {
      c0 = __builtin_amdgcn_mfma_f32_32x32x16_bf16(af[s], w2r[s],     c0, 0, 0, 0);
      c1 = __builtin_amdgcn_mfma_f32_32x32x16_bf16(af[s], w2r[8 + s], c1, 0, 0, 0);
    }

    // ---- epilogue: bias + relu + row-sum (row m=(r&3)+8*(r>>2)+4*half) ----
    if (cb + 32 <= cnt) {
      #pragma unroll
      for (int r = 0; r < 16; ++r) {
        sum0 += fmaxf(c0[r] + bv0, 0.f);
        sum1 += fmaxf(c1[r] + bv1, 0.f);
      }
    } else {
      #pragma unroll
      for (int r = 0; r < 16; ++r) {
        const int q = cb + (r & 3) + ((r >> 2) << 3) + (half << 2);
        if (q < cnt) {
          sum0 += fmaxf(c0[r] + bv0, 0.f);
          sum1 += fmaxf(c1[r] + bv1, 0.f);
        }
      }
    }
    xf = nxf;
  }

  // fold halves; two waves share each col-half -> LDS atomics
  sum0 += __shfl_xor(sum0, 32);
  sum1 += __shfl_xor(sum1, 32);
  if (half == 0) {
    atomicAdd(&sAcc[ch * 64 + l31],      sum0);
    atomicAdd(&sAcc[ch * 64 + 32 + l31], sum1);
  }
  __syncthreads();
  if (t < HID_) part[((size_t)b * NT_ + blockIdx.x) * HID_ + t] = sAcc[t];
}

// acc = sum partials; h3 = relu(acc@W3+b3); h4 = relu(h3@W4+b4);
// out = [x[:,i,:] | h4] @ W5 + b5   (all fp32, exact)
__global__ void tail_kernel(
    const float* __restrict__ x, const float* __restrict__ part,
    const float* __restrict__ W3, const float* __restrict__ b3,
    const float* __restrict__ W4, const float* __restrict__ b4,
    const float* __restrict__ W5, const float* __restrict__ b5,
    const int* __restrict__ ip, float* __restrict__ out)
{
  const int b = blockIdx.x, t = threadIdx.x;   // 128 threads
  __shared__ float s0[HID_], s1[HID_], s2[HID_], se[DIM_];
  const int ii = __ldg(ip);
  if (t < DIM_) se[t] = x[((size_t)b * N_ + ii) * DIM_ + t];
  float a = 0.f;
  #pragma unroll
  for (int p = 0; p < NT_; ++p) a += part[((size_t)b * NT_ + p) * HID_ + t];
  s0[t] = a;
  __syncthreads();
  float v = b3[t];
  #pragma unroll 16
  for (int k = 0; k < HID_; ++k) v += s0[k] * W3[k * HID_ + t];
  s1[t] = fmaxf(v, 0.f);
  __syncthreads();
  float w = b4[t];
  #pragma unroll 16
  for (int k = 0; k < HID_; ++k) w += s1[k] * W4[k * HID_ + t];
  s2[t] = fmaxf(w, 0.f);
  __syncthreads();
  if (t < DIM_) {
    float o = b5[t];
    #pragma unroll
    for (int k = 0; k < DIM_; ++k) o += se[k] * W5[k * DIM_ + t];
    #pragma unroll 16
    for (int k = 0; k < HID_; ++k) o += s2[k] * W5[(DIM_ + k) * DIM_ + t];
    out[b * DIM_ + t] = o;
  }
}

extern "C" void kernel_launch(void* const* d_in, const int* in_sizes, int n_in,
                              void* d_out, int out_size, void* d_ws, size_t ws_size,
                              hipStream_t stream) {
  const float* x   = (const float*)d_in[0];
  const float* adj = (const float*)d_in[1];
  const float* W1  = (const float*)d_in[2];   // W_n2e [32,128]
  const float* b1  = (const float*)d_in[3];
  const float* W2  = (const float*)d_in[4];   // W_e2e [128,128]
  const float* b2  = (const float*)d_in[5];
  const float* W3  = (const float*)d_in[6];   // W_e2n
  const float* b3  = (const float*)d_in[7];
  const float* W4  = (const float*)d_in[8];   // W_n2n
  const float* b4  = (const float*)d_in[9];
  const float* W5  = (const float*)d_in[10];  // W_out [144,16]
  const float* b5  = (const float*)d_in[11];
  const int*   ip  = (const int*)d_in[12];
  float* out  = (float*)d_out;
  float* part = (float*)d_ws;                 // [B, NT_, HID] fp32 partials

  edge_kernel<<<dim3(NT_, B_), 256, 0, stream>>>(x, adj, W1, b1, W2, b2, ip, part);
  tail_kernel<<<B_, HID_, 0, stream>>>(x, part, W3, b3, W4, b4, W5, b5, ip, out);
}

// Round 11
// 122.625 us; speedup vs baseline: 1.6522x; 1.0092x over previous
//
#include <hip/hip_runtime.h>
#include <hip/hip_bf16.h>

#define B_    128
#define N_    4096
#define DIM_  16
#define HID_  128
#define NT_   4             // grid.x tiles -> 512 blocks, 2 resident/CU
#define ROWS_ (N_ / NT_)    // 1024 adj rows per block

typedef __bf16 bf16x8 __attribute__((ext_vector_type(8)));
typedef float floatx16 __attribute__((ext_vector_type(16)));
typedef unsigned int u32;

__device__ inline bf16x8 load_cvt8(const float* __restrict__ p) {
  const float4 u = *(const float4*)p;
  const float4 v = *(const float4*)(p + 4);
  bf16x8 r;
  r[0] = (__bf16)u.x; r[1] = (__bf16)u.y; r[2] = (__bf16)u.z; r[3] = (__bf16)u.w;
  r[4] = (__bf16)v.x; r[5] = (__bf16)v.y; r[6] = (__bf16)v.z; r[7] = (__bf16)v.w;
  return r;
}

// R11 = R10 + zero-shuffle repack. The stage-A C-layout vs stage-B A-operand
// mismatch is absorbed into a feature permutation pi = swap(bit2<->bit3) of k,
// applied to W2's ROWS at staging time (contraction sum_f h1[f] W2[f][c] is
// invariant when both sides are permuted). Then af[2ft][j]=relu(hc[j]),
// af[2ft+1][j]=relu(hc[8+j]) -- pure in-register, no ds_bpermute, no selects.
// Wave tile 32 rows x 64 cols; W2 B-frags register-resident (read once).
__global__ __launch_bounds__(256, 2) void edge_kernel(
    const float* __restrict__ x, const float* __restrict__ adj,
    const float* __restrict__ W1, const float* __restrict__ b1,
    const float* __restrict__ W2, const float* __restrict__ b2,
    const int* __restrict__ ip, float* __restrict__ part)
{
  // sW2: col c = 128 contiguous bf16 (16 granules of 8), granule slot gg^(c&15),
  // rows bit2<->bit3-permuted: granule gg element j holds
  // W2[16*(gg>>1) + 8*(j>>2) + 4*(gg&1) + (j&3)][c].
  __shared__ __align__(16) __bf16 sW2[HID_ * HID_];
  __shared__ __align__(16) float sW1s[DIM_][HID_];   // W1 starter rows, coalesced staged
  __shared__ int   sIdx[ROWS_ + 192];
  __shared__ float sAcc[HID_];
  __shared__ float sB1[HID_];
  __shared__ float sEnder[DIM_];
  __shared__ int   sCnt;

  const int t  = threadIdx.x;
  const int b  = blockIdx.y;
  const int n0 = blockIdx.x * ROWS_;
  const int ii = __ldg(ip);

  const int wave = t >> 6, lane = t & 63;
  const int half = lane >> 5, l31 = lane & 31;
  const int rg = wave >> 1;           // row-group: chunks rg*32, step 64
  const int ch = wave & 1;            // col-half: cols ch*64 .. ch*64+63

  if (t == 0) sCnt = 0;
  if (t < HID_) sAcc[t] = 0.f;
  if (t < DIM_) sEnder[t] = x[((size_t)b * N_ + ii) * DIM_ + t];
  __syncthreads();

  // ---- ballot-based compaction: 1 LDS atomic per wave-iter ----
  #pragma unroll
  for (int r = t; r < ROWS_; r += 256) {
    const bool act = adj[n0 + r] != 0.f;
    const unsigned long long m = __ballot(act);
    int base = 0;
    if (lane == 0) base = atomicAdd(&sCnt, __popcll(m));
    base = __shfl(base, 0);
    if (act) {
      const int pre = __builtin_amdgcn_mbcnt_hi((u32)(m >> 32),
                      __builtin_amdgcn_mbcnt_lo((u32)m, 0));
      sIdx[base + pre] = n0 + r;
    }
  }

  // ---- W1 starter rows -> LDS, fully coalesced ----
  #pragma unroll
  for (int e = t; e < DIM_ * HID_; e += 256) sW1s[e >> 7][e & 127] = W1[e];

  // ---- stage W2^T into LDS, bf16, XOR-swizzled granules, pi-permuted rows ----
  #pragma unroll
  for (int e = 0; e < 8; ++e) {
    const int G = t * 8 + e;            // granule id: c = G>>4, gg = G&15
    const int c = G >> 4, gg = G & 15;
    bf16x8 v;
    #pragma unroll
    for (int j = 0; j < 8; ++j) {
      const int row = ((gg >> 1) << 4) + ((j >> 2) << 3) + ((gg & 1) << 2) + (j & 3);
      v[j] = (__bf16)W2[row * HID_ + c];
    }
    *(bf16x8*)&sW2[(c << 7) + ((gg ^ (c & 15)) << 3)] = v;
  }

  // ---- cooperative ender-fold: sB1[f] = b1[f] + ender . W1[16:32, f] ----
  if (t < HID_) {
    float s = b1[t];
    #pragma unroll
    for (int k = 0; k < DIM_; ++k) s += sEnder[k] * W1[(DIM_ + k) * HID_ + t];
    sB1[t] = s;
  }

  const float bv0 = b2[ch * 64 + l31], bv1 = b2[ch * 64 + 32 + l31];

  __syncthreads();                       // sIdx/sCnt/sW2/sW1s/sB1 ready
  const int cnt = sCnt;
  const int nch64 = (cnt + 63) >> 6;
  const int end = nch64 * 64;
  for (int p = cnt + t; p < end + 128; p += 256) sIdx[p] = n0;  // pad + prefetch slack

  // W1^T A-frags from LDS (m=feat=l31+32ft, k=half*8+j)
  bf16x8 w1f[4];
  #pragma unroll
  for (int ft = 0; ft < 4; ++ft) {
    bf16x8 v;
    #pragma unroll
    for (int j = 0; j < 8; ++j) v[j] = (__bf16)sW1s[half * 8 + j][ft * 32 + l31];
    w1f[ft] = v;
  }

  // ---- W2 B-frags for this wave's col-half: read ONCE from swizzled LDS ----
  bf16x8 w2r[16];                        // [s] = col-tile0, [8+s] = col-tile1
  {
    const int c0 = ch * 64 + l31;
    const __bf16* base0 = &sW2[(c0 << 7)];
    const __bf16* base1 = &sW2[((c0 + 32) << 7)];
    #pragma unroll
    for (int s = 0; s < 8; ++s) {
      const int gp = ((s << 1) + half) ^ (c0 & 15);
      w2r[s]     = *(const bf16x8*)(base0 + (gp << 3));
      w2r[8 + s] = *(const bf16x8*)(base1 + (gp << 3));
    }
  }

  // bias delivered via spare-K MFMA (k=0: bf16 hi, k=1: bf16 residual)
  bf16x8 a2f[4], onef;
  #pragma unroll
  for (int j = 0; j < 8; ++j) onef[j] = (__bf16)0.f;
  if (half == 0) { onef[0] = (__bf16)1.f; onef[1] = (__bf16)1.f; }
  #pragma unroll
  for (int ft = 0; ft < 4; ++ft) {
    bf16x8 v;
    #pragma unroll
    for (int j = 0; j < 8; ++j) v[j] = (__bf16)0.f;
    if (half == 0) {
      const float s = sB1[ft * 32 + l31];
      const __bf16 hi = (__bf16)s;
      v[0] = hi;
      v[1] = (__bf16)(s - (float)hi);
    }
    a2f[ft] = v;
  }
  __syncthreads();                       // pad visible

  float sum0 = 0.f, sum1 = 0.f;
  floatx16 zf;
  #pragma unroll
  for (int r = 0; r < 16; ++r) zf[r] = 0.f;

  // prefetch first gather (pad guarantees sIdx valid)
  int cb = rg * 32;
  bf16x8 xf;
  {
    const int row = sIdx[cb + l31];
    xf = load_cvt8(&x[((size_t)b * N_ + row) * DIM_ + half * 8]);
  }

  for (; cb < end; cb += 64) {
    const int nrow = sIdx[cb + 64 + l31];            // next iter (pad-safe)

    // ---- stage A: h1^T tiles; pi-permutation makes the repack register-local ----
    bf16x8 af[8];                        // stage-B A-frags, k = s*16 + half*8 + j
    #pragma unroll
    for (int ft = 0; ft < 4; ++ft) {
      floatx16 hc = __builtin_amdgcn_mfma_f32_32x32x16_bf16(w1f[ft], xf, zf, 0, 0, 0);
      hc = __builtin_amdgcn_mfma_f32_32x32x16_bf16(a2f[ft], onef, hc, 0, 0, 0);
      bf16x8 a0, a1;
      #pragma unroll
      for (int j = 0; j < 8; ++j) {
        a0[j] = (__bf16)fmaxf(hc[j],     0.f);
        a1[j] = (__bf16)fmaxf(hc[8 + j], 0.f);
      }
      af[2 * ft]     = a0;
      af[2 * ft + 1] = a1;
    }

    // prefetch next x gather; its waitcnt lands after stage B
    const bf16x8 nxf = load_cvt8(&x[((size_t)b * N_ + nrow) * DIM_ + half * 8]);

    // ---- stage B: 32 rows x 64 cols, K=128; B-frags from REGISTERS ----
    floatx16 c0 = zf, c1 = zf;
    #pragma unroll
    for (int s = 0; s < 8; ++s) {
      c0 = __builtin_amdgcn_mfma_f32_32x32x16_bf16(af[s], w2r[s],     c0, 0, 0, 0);
      c1 = __builtin_amdgcn_mfma_f32_32x32x16_bf16(af[s], w2r[8 + s], c1, 0, 0, 0);
    }

    // ---- epilogue: bias + relu + row-sum (row m=(r&3)+8*(r>>2)+4*half) ----
    if (cb + 32 <= cnt) {
      #pragma unroll
      for (int r = 0; r < 16; ++r) {
        sum0 += fmaxf(c0[r] + bv0, 0.f);
        sum1 += fmaxf(c1[r] + bv1, 0.f);
      }
    } else {
      #pragma unroll
      for (int r = 0; r < 16; ++r) {
        const int q = cb + (r & 3) + ((r >> 2) << 3) + (half << 2);
        if (q < cnt) {
          sum0 += fmaxf(c0[r] + bv0, 0.f);
          sum1 += fmaxf(c1[r] + bv1, 0.f);
        }
      }
    }
    xf = nxf;
  }

  // fold halves; two waves share each col-half -> LDS atomics
  sum0 += __shfl_xor(sum0, 32);
  sum1 += __shfl_xor(sum1, 32);
  if (half == 0) {
    atomicAdd(&sAcc[ch * 64 + l31],      sum0);
    atomicAdd(&sAcc[ch * 64 + 32 + l31], sum1);
  }
  __syncthreads();
  if (t < HID_) part[((size_t)b * NT_ + blockIdx.x) * HID_ + t] = sAcc[t];
}

// acc = sum partials; h3 = relu(acc@W3+b3); h4 = relu(h3@W4+b4);
// out = [x[:,i,:] | h4] @ W5 + b5   (all fp32, exact)
__global__ void tail_kernel(
    const float* __restrict__ x, const float* __restrict__ part,
    const float* __restrict__ W3, const float* __restrict__ b3,
    const float* __restrict__ W4, const float* __restrict__ b4,
    const float* __restrict__ W5, const float* __restrict__ b5,
    const int* __restrict__ ip, float* __restrict__ out)
{
  const int b = blockIdx.x, t = threadIdx.x;   // 128 threads
  __shared__ float s0[HID_], s1[HID_], s2[HID_], se[DIM_];
  const int ii = __ldg(ip);
  if (t < DIM_) se[t] = x[((size_t)b * N_ + ii) * DIM_ + t];
  float a = 0.f;
  #pragma unroll
  for (int p = 0; p < NT_; ++p) a += part[((size_t)b * NT_ + p) * HID_ + t];
  s0[t] = a;
  __syncthreads();
  float v = b3[t];
  #pragma unroll 16
  for (int k = 0; k < HID_; ++k) v += s0[k] * W3[k * HID_ + t];
  s1[t] = fmaxf(v, 0.f);
  __syncthreads();
  float w = b4[t];
  #pragma unroll 16
  for (int k = 0; k < HID_; ++k) w += s1[k] * W4[k * HID_ + t];
  s2[t] = fmaxf(w, 0.f);
  __syncthreads();
  if (t < DIM_) {
    float o = b5[t];
    #pragma unroll
    for (int k = 0; k < DIM_; ++k) o += se[k] * W5[k * DIM_ + t];
    #pragma unroll 16
    for (int k = 0; k < HID_; ++k) o += s2[k] * W5[(DIM_ + k) * DIM_ + t];
    out[b * DIM_ + t] = o;
  }
}

extern "C" void kernel_launch(void* const* d_in, const int* in_sizes, int n_in,
                              void* d_out, int out_size, void* d_ws, size_t ws_size,
                              hipStream_t stream) {
  const float* x   = (const float*)d_in[0];
  const float* adj = (const float*)d_in[1];
  const float* W1  = (const float*)d_in[2];   // W_n2e [32,128]
  const float* b1  = (const float*)d_in[3];
  const float* W2  = (const float*)d_in[4];   // W_e2e [128,128]
  const float* b2  = (const float*)d_in[5];
  const float* W3  = (const float*)d_in[6];   // W_e2n
  const float* b3  = (const float*)d_in[7];
  const float* W4  = (const float*)d_in[8];   // W_n2n
  const float* b4  = (const float*)d_in[9];
  const float* W5  = (const float*)d_in[10];  // W_out [144,16]
  const float* b5  = (const float*)d_in[11];
  const int*   ip  = (const int*)d_in[12];
  float* out  = (float*)d_out;
  float* part = (float*)d_ws;                 // [B, NT_, HID] fp32 partials

  edge_kernel<<<dim3(NT_, B_), 256, 0, stream>>>(x, adj, W1, b1, W2, b2, ip, part);
  tail_kernel<<<B_, HID_, 0, stream>>>(x, part, W3, b3, W4, b4, W5, b5, ip, out);
}